// Round 1
// baseline (4002.676 us; speedup 1.0000x reference)
//
#include <hip/hip_runtime.h>
#include <math.h>

#define B_ 2
#define H_ 16
#define N_ 2048
#define D_ 64
#define TI 16
#define TJ 8

// ---------------------------------------------------------------------------
// Kernel 1: talking-heads premix of q and k with W_pre:
//   qp[b,e,n,d] = sum_f Wpre[e,f] * q[b,f,n,d]   (same for k)
// One thread per (b,n,d); tensor selected by blockIdx>>10. Coalesced in d.
// ---------------------------------------------------------------------------
__global__ __launch_bounds__(256) void premix_kernel(const float* __restrict__ q,
                                                     const float* __restrict__ k,
                                                     const float* __restrict__ Wpre,
                                                     float* __restrict__ qp,
                                                     float* __restrict__ kp) {
    __shared__ float w[H_ * H_];
    int tid = threadIdx.x;
    w[tid] = Wpre[tid];          // 256 threads == 16x16 weights
    __syncthreads();

    int tensor = blockIdx.x >> 10;               // 0 = q, 1 = k
    int gid = ((blockIdx.x & 1023) << 8) | tid;  // 0 .. B*N*D-1
    int b = gid >> 17;                           // N*D = 131072
    int nd = gid & 131071;

    const float* src = tensor ? k : q;
    float* dst = tensor ? kp : qp;
    const float* base = src + ((size_t)b * H_) * (N_ * D_) + nd;
    float x[H_];
#pragma unroll
    for (int f = 0; f < H_; f++) x[f] = base[(size_t)f * (N_ * D_)];
    float* ob = dst + ((size_t)b * H_) * (N_ * D_) + nd;
#pragma unroll
    for (int e = 0; e < H_; e++) {
        float acc = 0.f;
#pragma unroll
        for (int f = 0; f < H_; f++) acc += w[e * H_ + f] * x[f];
        ob[(size_t)e * (N_ * D_)] = acc;
    }
}

// ---------------------------------------------------------------------------
// Kernel 2: fused talking-heads causal attention.
// Block = (b, 16-row query tile), all 16 heads. 256 threads:
//   role A (scores / P):  f = tid>>4, i' = tid&15
//   role B (mix):         e = tid>>4, i' = tid&15
//   role C (PV accum):    e = tid>>4, d-quad = tid&15
// Phase 1: l[f,i] = sum_{j<=i} exp(s)   (scores small; no max needed)
// Phase 2: P = exp(s)/l -> LDS; Pmix = W_post @ P; out[e,i,:] += Pmix @ V[e]
// Softmax math entirely in fp32.
// ---------------------------------------------------------------------------
__global__ __launch_bounds__(256) void attend_kernel(const float* __restrict__ qp,
                                                     const float* __restrict__ kp,
                                                     const float* __restrict__ v,
                                                     const float* __restrict__ Wpost,
                                                     float* __restrict__ out) {
    // K tile is stored f-rotated by 2 float4-chunks to break the 4-way
    // bank conflict from the 512-float f-stride (f-groups land on distinct banks).
    __shared__ float ks[H_][TJ][D_];
    __shared__ float vs[H_][TJ][D_];
    __shared__ float Pb[H_][TI][12];   // pad 8->12 keeps rows 16B-aligned
    __shared__ float Pm[H_][TI][12];

    int tid = threadIdx.x;
    int tf = tid >> 4;
    int ti = tid & 15;
    int b  = blockIdx.x >> 7;       // 128 i-tiles per batch
    int it = blockIdx.x & 127;
    int i0 = it * TI;
    int i  = i0 + ti;               // role-A query row
    const float scale = 1.0f / 32.0f;  // 1/(sqrt(H)*sqrt(D))

    // q' row (b, f=tf, i, :) -> 64 floats in registers
    float4 qreg[16];
    {
        const float4* qrow = (const float4*)(qp + (((size_t)b * H_ + tf) * N_ + i) * D_);
#pragma unroll
        for (int c = 0; c < 16; c++) qreg[c] = qrow[c];
    }
    // W_post row for e = tf
    float wpost[16];
#pragma unroll
    for (int f = 0; f < 16; f++) wpost[f] = Wpost[tf * H_ + f];

    float4 oacc[16];
#pragma unroll
    for (int r = 0; r < 16; r++) oacc[r] = make_float4(0.f, 0.f, 0.f, 0.f);

    int i_max = i0 + TI - 1;
    int njt = (i_max / TJ) + 1;

    const float* kbase = kp + ((size_t)b * H_) * N_ * D_;
    const float* vbase = v  + ((size_t)b * H_) * N_ * D_;

    // ---------------- phase 1: softmax denominators ----------------
    float l = 0.f;
    for (int t = 0; t < njt; t++) {
        int j0 = t * TJ;
#pragma unroll
        for (int u = 0; u < 8; u++) {   // stage K tile: 2048 float4, 8/thread
            int g = (u << 8) | tid;
            int d4 = g & 15, jj = (g >> 4) & 7, f = g >> 7;
            float4 val = *(const float4*)(kbase + (((size_t)f * N_) + j0 + jj) * D_ + (d4 << 2));
            int d4r = (d4 + 2 * f) & 15;
            *(float4*)&ks[f][jj][d4r << 2] = val;
        }
        __syncthreads();
#pragma unroll
        for (int jj = 0; jj < TJ; jj++) {
            float4 s4 = make_float4(0.f, 0.f, 0.f, 0.f);
#pragma unroll
            for (int c = 0; c < 16; c++) {
                int cr = (c + 2 * tf) & 15;
                float4 kv = *(const float4*)&ks[tf][jj][cr << 2];
                float4 qv = qreg[c];
                s4.x += qv.x * kv.x; s4.y += qv.y * kv.y;
                s4.z += qv.z * kv.z; s4.w += qv.w * kv.w;
            }
            float s = (s4.x + s4.y) + (s4.z + s4.w);
            if (j0 + jj <= i) l += __expf(s * scale);
        }
        __syncthreads();
    }
    float linv = 1.0f / l;

    // ---------------- phase 2: P, mix, PV ----------------
    for (int t = 0; t < njt; t++) {
        int j0 = t * TJ;
#pragma unroll
        for (int u = 0; u < 8; u++) {   // stage K and V tiles
            int g = (u << 8) | tid;
            int d4 = g & 15, jj = (g >> 4) & 7, f = g >> 7;
            size_t off = (((size_t)f * N_) + j0 + jj) * D_ + (d4 << 2);
            float4 kvv = *(const float4*)(kbase + off);
            int d4r = (d4 + 2 * f) & 15;
            *(float4*)&ks[f][jj][d4r << 2] = kvv;
            float4 vvv = *(const float4*)(vbase + off);
            *(float4*)&vs[f][jj][d4 << 2] = vvv;
        }
        __syncthreads();
        // scores -> P
#pragma unroll
        for (int jj = 0; jj < TJ; jj++) {
            float4 s4 = make_float4(0.f, 0.f, 0.f, 0.f);
#pragma unroll
            for (int c = 0; c < 16; c++) {
                int cr = (c + 2 * tf) & 15;
                float4 kv = *(const float4*)&ks[tf][jj][cr << 2];
                float4 qv = qreg[c];
                s4.x += qv.x * kv.x; s4.y += qv.y * kv.y;
                s4.z += qv.z * kv.z; s4.w += qv.w * kv.w;
            }
            float s = (s4.x + s4.y) + (s4.z + s4.w);
            float p = (j0 + jj <= i) ? __expf(s * scale) * linv : 0.f;
            Pb[tf][ti][jj] = p;
        }
        __syncthreads();
        // mix: Pm[e=tf][i'=ti][jj] = sum_f wpost[f] * Pb[f][ti][jj]
        {
            float4 a0 = make_float4(0.f, 0.f, 0.f, 0.f);
            float4 a1 = make_float4(0.f, 0.f, 0.f, 0.f);
#pragma unroll
            for (int f = 0; f < 16; f++) {
                float4 p0 = *(const float4*)&Pb[f][ti][0];
                float4 p1 = *(const float4*)&Pb[f][ti][4];
                float wv = wpost[f];
                a0.x += wv * p0.x; a0.y += wv * p0.y; a0.z += wv * p0.z; a0.w += wv * p0.w;
                a1.x += wv * p1.x; a1.y += wv * p1.y; a1.z += wv * p1.z; a1.w += wv * p1.w;
            }
            *(float4*)&Pm[tf][ti][0] = a0;
            *(float4*)&Pm[tf][ti][4] = a1;
        }
        __syncthreads();
        // PV: thread (e=tf, dq=ti): oacc[r] += sum_jj Pm[e][r][jj] * V[e][jj][dq]
        {
            float4 vv[TJ];
#pragma unroll
            for (int jj = 0; jj < TJ; jj++) vv[jj] = *(const float4*)&vs[tf][jj][ti << 2];
#pragma unroll
            for (int r = 0; r < 16; r++) {
                float4 pm0 = *(const float4*)&Pm[tf][r][0];
                float4 pm1 = *(const float4*)&Pm[tf][r][4];
                float pmv[8] = {pm0.x, pm0.y, pm0.z, pm0.w, pm1.x, pm1.y, pm1.z, pm1.w};
                float4 o = oacc[r];
#pragma unroll
                for (int jj = 0; jj < 8; jj++) {
                    o.x += pmv[jj] * vv[jj].x;
                    o.y += pmv[jj] * vv[jj].y;
                    o.z += pmv[jj] * vv[jj].z;
                    o.w += pmv[jj] * vv[jj].w;
                }
                oacc[r] = o;
            }
        }
        __syncthreads();
    }

    // store: out[b][e=tf][i0+r][4*ti .. 4*ti+3]
    float* ob = out + (((size_t)b * H_ + tf) * N_ + i0) * D_ + (ti << 2);
#pragma unroll
    for (int r = 0; r < 16; r++) {
        *(float4*)(ob + (size_t)r * D_) = oacc[r];
    }
}

extern "C" void kernel_launch(void* const* d_in, const int* in_sizes, int n_in,
                              void* d_out, int out_size, void* d_ws, size_t ws_size,
                              hipStream_t stream) {
    const float* q     = (const float*)d_in[0];
    const float* k     = (const float*)d_in[1];
    const float* v     = (const float*)d_in[2];
    const float* Wpre  = (const float*)d_in[3];
    const float* Wpost = (const float*)d_in[4];
    float* out = (float*)d_out;

    float* qp = (float*)d_ws;                        // 16 MB
    float* kp = qp + (size_t)B_ * H_ * N_ * D_;      // +16 MB

    premix_kernel<<<2048, 256, 0, stream>>>(q, k, Wpre, qp, kp);
    attend_kernel<<<B_ * (N_ / TI), 256, 0, stream>>>(qp, kp, v, Wpost, out);
}

// Round 2
// 738.709 us; speedup vs baseline: 5.4185x; 5.4185x over previous
//
#include <hip/hip_runtime.h>
#include <math.h>

typedef _Float16 Hh;
typedef __attribute__((ext_vector_type(8))) _Float16 half8;
typedef __attribute__((ext_vector_type(4))) _Float16 half4;
typedef __attribute__((ext_vector_type(4))) float float4v;

#define B_ 2
#define H_ 16
#define N_ 2048
#define D_ 64
#define ND_ (N_*D_)
#define C1 0.04508422f   // (1/32)*log2(e); softmax base-2 consistently in both passes

// ---------------------------------------------------------------------------
// K1: prep. blocks 0..2047: premix q,k with W_pre -> f16 [b][e][n][d].
//     blocks 2048..3071: transpose v -> f16 vt[b][e][d][j].
// ---------------------------------------------------------------------------
__global__ __launch_bounds__(256) void prep_kernel(const float* __restrict__ q,
    const float* __restrict__ k, const float* __restrict__ v,
    const float* __restrict__ Wpre,
    Hh* __restrict__ qb, Hh* __restrict__ kb, Hh* __restrict__ vt)
{
    int tid = threadIdx.x;
    int bid = blockIdx.x;
    if (bid < 2048) {
        __shared__ float wsh[256];
        wsh[tid] = Wpre[tid];
        __syncthreads();
        int tensor = bid >> 10;
        int gid = ((bid & 1023) << 8) | tid;
        int b = gid >> 17;
        int nd = gid & (ND_-1);
        const float* src = tensor ? k : q;
        Hh* dst = tensor ? kb : qb;
        const float* base = src + (size_t)b*H_*ND_ + nd;
        float x[16];
        #pragma unroll
        for (int f=0; f<16; f++) x[f] = base[(size_t)f*ND_];
        Hh* ob = dst + (size_t)b*H_*ND_ + nd;
        #pragma unroll
        for (int e=0; e<16; e++) {
            float acc = 0.f;
            #pragma unroll
            for (int f=0; f<16; f++) acc += wsh[e*16+f]*x[f];
            ob[(size_t)e*ND_] = (Hh)acc;
        }
    } else {
        __shared__ Hh tile[64][66];
        int tb = bid - 2048;
        int be = tb >> 5;             // b*16+e
        int j0 = (tb & 31) << 6;
        const float* vb = v + (size_t)be*ND_;
        #pragma unroll
        for (int u=0; u<16; u++) {
            int idx = (u<<8) | tid;
            int jp = idx >> 6, d = idx & 63;
            tile[jp][d] = (Hh)vb[(size_t)(j0+jp)*64 + d];
        }
        __syncthreads();
        Hh* vo = vt + (size_t)be*ND_;
        #pragma unroll
        for (int u=0; u<16; u++) {
            int idx = (u<<8) | tid;
            int d = idx >> 6, jp = idx & 63;
            vo[(size_t)d*N_ + j0 + jp] = tile[jp][d];
        }
    }
}

// ---------------------------------------------------------------------------
// K2: denominators. Block=(b, 16-row i-tile); wave w = j-chunk w of 64-j tile.
// lg2l[b,f,i] = log2( sum_{j<=i} exp2(s*C1) ), s = q'.k' via MFMA.
// ---------------------------------------------------------------------------
__global__ __launch_bounds__(256) void denom_kernel(const Hh* __restrict__ qb,
    const Hh* __restrict__ kb, float* __restrict__ lg2l)
{
    __shared__ float part[4][16][16];
    int tid = threadIdx.x;
    int lane = tid & 63, w = tid >> 6;
    int quad = lane >> 4, col = lane & 15;
    int idx = 255 - (int)blockIdx.x;          // big strips first
    int b = idx & 1, it = idx >> 1;
    int i0 = it << 4, imax = i0 + 15;

    float lacc[64];
    #pragma unroll
    for (int i=0;i<64;i++) lacc[i]=0.f;

    int njt = imax/64 + 1;
    for (int t=0;t<njt;t++) {
        int jc = t*64 + 16*w;
        if (jc <= imax) {                     // wave-uniform
            #pragma unroll
            for (int f=0; f<16; f++) {
                const Hh* qr = qb + ((size_t)(b*16+f)*N_ + i0+col)*64 + quad*8;
                const Hh* kr = kb + ((size_t)(b*16+f)*N_ + jc+col)*64 + quad*8;
                half8 a0 = *(const half8*)qr;
                half8 a1 = *(const half8*)(qr+32);
                half8 b0 = *(const half8*)kr;
                half8 b1 = *(const half8*)(kr+32);
                float4v s = {0.f,0.f,0.f,0.f};
                s = __builtin_amdgcn_mfma_f32_16x16x32_f16(a0,b0,s,0,0,0);
                s = __builtin_amdgcn_mfma_f32_16x16x32_f16(a1,b1,s,0,0,0);
                #pragma unroll
                for (int r=0;r<4;r++) {
                    int ir = i0 + quad*4 + r;
                    int jl = jc + col;
                    float ev = (jl <= ir) ? __builtin_amdgcn_exp2f(s[r]*C1) : 0.f;
                    lacc[f*4+r] += ev;
                }
            }
        }
    }
    #pragma unroll
    for (int f=0; f<16; f++) {
      #pragma unroll
      for (int r=0;r<4;r++) {
        float vs = lacc[f*4+r];
        vs += __shfl_xor(vs, 1);
        vs += __shfl_xor(vs, 2);
        vs += __shfl_xor(vs, 4);
        vs += __shfl_xor(vs, 8);
        if (col == 0) part[w][f][quad*4+r] = vs;
      }
    }
    __syncthreads();
    int f = tid >> 4, i = tid & 15;
    float l = part[0][f][i]+part[1][f][i]+part[2][f][i]+part[3][f][i];
    lg2l[(size_t)(b*16+f)*N_ + i0 + i] = __builtin_amdgcn_logf(l);
}

// ---------------------------------------------------------------------------
// K3: main fused pass. Block=(b, 16-row i-tile), 4 waves = 4 j-chunks (TJ=64).
// Per tile: scores (MFMA f16) -> p=exp2(s*C1-lg2l) -> Pbuf(LDS, per-wave) ->
// head-mix via mfma_16x16x16f16 (A=W_post) -> pm (LDS, XOR-swizzled chunks)
// -> PV via MFMA with vt B-frags from global. Wave w accumulates e in [4w,4w+4).
// ---------------------------------------------------------------------------
__global__ __launch_bounds__(256,2) void attend_kernel(const Hh* __restrict__ qb,
    const Hh* __restrict__ kb, const Hh* __restrict__ vt,
    const float* __restrict__ lg2l, const float* __restrict__ Wpost,
    float* __restrict__ out)
{
    __shared__ Hh Pbuf[4][256][20];   // [wave][point=i'*16+j'][f]  40960 B
    __shared__ Hh pm[16][16][68];     // [i'][e][8x8 chunks, chunk^ (i'&7)] 34816 B
    __shared__ float lgl[16][16];

    int tid = threadIdx.x;
    int lane = tid & 63, w = tid >> 6;
    int quad = lane >> 4, col = lane & 15;
    int idx = 255 - (int)blockIdx.x;
    int b = idx & 1, it = idx >> 1;
    int i0 = it << 4, imax = i0 + 15;

    lgl[tid>>4][tid&15] = lg2l[(size_t)(b*16+(tid>>4))*N_ + i0 + (tid&15)];

    half4 wf;   // A-frag of W_post for 16x16x16f16: A[m=e=col][k=f=quad*4+j]
    #pragma unroll
    for (int j=0;j<4;j++) wf[j] = (Hh)Wpost[col*16 + quad*4 + j];

    float4v acc[4][4];
    #pragma unroll
    for (int x=0;x<4;x++)
      #pragma unroll
      for (int y=0;y<4;y++) acc[x][y] = (float4v){0.f,0.f,0.f,0.f};

    __syncthreads();

    int njt = imax/64 + 1;
    for (int t=0;t<njt;t++) {
        int j0 = t*64;
        int jc = j0 + 16*w;
        if (jc <= imax) {
            // ---- scores + exp for all 16 f at this wave's 16-j chunk ----
            #pragma unroll
            for (int f=0; f<16; f++) {
                const Hh* qr = qb + ((size_t)(b*16+f)*N_ + i0+col)*64 + quad*8;
                const Hh* kr = kb + ((size_t)(b*16+f)*N_ + jc+col)*64 + quad*8;
                half8 a0 = *(const half8*)qr;
                half8 a1 = *(const half8*)(qr+32);
                half8 b0 = *(const half8*)kr;
                half8 b1 = *(const half8*)(kr+32);
                float4v s = {0.f,0.f,0.f,0.f};
                s = __builtin_amdgcn_mfma_f32_16x16x32_f16(a0,b0,s,0,0,0);
                s = __builtin_amdgcn_mfma_f32_16x16x32_f16(a1,b1,s,0,0,0);
                float4v lg = *(const float4v*)&lgl[f][quad*4];
                #pragma unroll
                for (int r=0;r<4;r++) {
                    int ir = i0 + quad*4 + r;
                    int jl = jc + col;
                    float p = (jl <= ir) ? __builtin_amdgcn_exp2f(s[r]*C1 - lg[r]) : 0.f;
                    Pbuf[w][(quad*4+r)*16 + col][f] = (Hh)p;
                }
            }
            // ---- head mix: Pm[e][point] = W_post . P  (own-wave LDS only) ----
            #pragma unroll
            for (int g=0; g<16; g++) {
                half4 bf = *(const half4*)&Pbuf[w][g*16 + col][quad*4];
                float4v c = {0.f,0.f,0.f,0.f};
                c = __builtin_amdgcn_mfma_f32_16x16x16f16(wf, bf, c, 0,0,0);
                int jj = 16*w + col;
                int chunk = (jj>>3) ^ (g&7);
                int off = chunk*8 + (jj&7);
                #pragma unroll
                for (int r=0;r<4;r++) pm[g][quad*4+r][off] = (Hh)c[r];
            }
        } else {
            int jj = 16*w + col;
            #pragma unroll
            for (int g=0; g<16; g++) {
                int chunk = (jj>>3) ^ (g&7);
                int off = chunk*8 + (jj&7);
                #pragma unroll
                for (int r=0;r<4;r++) pm[g][quad*4+r][off] = (Hh)0.f;
            }
        }
        __syncthreads();
        // ---- PV: wave w owns e in [4w, 4w+4), full d=64 ----
        #pragma unroll
        for (int el=0; el<4; el++) {
            int e = w*4 + el;
            #pragma unroll
            for (int kc=0; kc<2; kc++) {
                if (j0 + kc*32 <= imax) {       // wave-uniform skip
                    int chunk = (kc*4 + quad) ^ (col & 7);
                    const Hh* pp = &pm[col][e][chunk*8];
                    half4 p0 = *(const half4*)pp;
                    half4 p1 = *(const half4*)(pp+4);
                    half8 af;
                    #pragma unroll
                    for (int z=0;z<4;z++){ af[z]=p0[z]; af[4+z]=p1[z]; }
                    #pragma unroll
                    for (int nc=0; nc<4; nc++) {
                        const Hh* vr = vt + ((size_t)(b*16+e)*64 + nc*16 + col)*N_
                                          + j0 + kc*32 + quad*8;
                        half8 vfr = *(const half8*)vr;
                        acc[el][nc] = __builtin_amdgcn_mfma_f32_16x16x32_f16(af, vfr, acc[el][nc], 0,0,0);
                    }
                }
            }
        }
        __syncthreads();
    }
    #pragma unroll
    for (int el=0; el<4; el++) {
        int e = w*4 + el;
        #pragma unroll
        for (int nc=0; nc<4; nc++) {
          #pragma unroll
          for (int r=0;r<4;r++)
            out[((size_t)(b*16+e)*N_ + i0 + quad*4 + r)*64 + nc*16 + col] = acc[el][nc][r];
        }
    }
}

extern "C" void kernel_launch(void* const* d_in, const int* in_sizes, int n_in,
                              void* d_out, int out_size, void* d_ws, size_t ws_size,
                              hipStream_t stream) {
    const float* q     = (const float*)d_in[0];
    const float* k     = (const float*)d_in[1];
    const float* v     = (const float*)d_in[2];
    const float* Wpre  = (const float*)d_in[3];
    const float* Wpost = (const float*)d_in[4];
    float* out = (float*)d_out;

    size_t tsz = (size_t)B_*H_*N_*D_;       // 4 Mi halves = 8 MB
    Hh* qb = (Hh*)d_ws;
    Hh* kb = qb + tsz;
    Hh* vt = kb + tsz;
    float* lgw = (float*)(vt + tsz);        // 24 MB offset, 512 KB

    prep_kernel<<<3072, 256, 0, stream>>>(q, k, v, Wpre, qb, kb, vt);
    denom_kernel<<<256, 256, 0, stream>>>(qb, kb, lgw);
    attend_kernel<<<256, 256, 0, stream>>>(qb, kb, vt, lgw, Wpost, out);
}